// Round 1
// baseline (7852.141 us; speedup 1.0000x reference)
//
#include <hip/hip_runtime.h>

#define D 128
#define NUSERS 100000
#define NITEMS 50000
#define NNODES 150000
#define NEDGES 3200000
#define NSEL 2048
#define NLAYERS 3

// cur = concat(user_emb, item_emb), float4-vectorized grid-stride copy
__global__ void k_init(const float4* __restrict__ u4, const float4* __restrict__ i4,
                       float4* __restrict__ cur) {
    size_t total = (size_t)NNODES * D / 4;
    size_t ubound = (size_t)NUSERS * D / 4;
    size_t stride = (size_t)gridDim.x * blockDim.x;
    for (size_t i = (size_t)blockIdx.x * blockDim.x + threadIdx.x; i < total; i += stride)
        cur[i] = (i < ubound) ? u4[i] : i4[i - ubound];
}

__global__ void k_zero(float4* __restrict__ p, size_t n4) {
    size_t stride = (size_t)gridDim.x * blockDim.x;
    float4 z = make_float4(0.f, 0.f, 0.f, 0.f);
    for (size_t i = (size_t)blockIdx.x * blockDim.x + threadIdx.x; i < n4; i += stride)
        p[i] = z;
}

// one wave per edge: 64 lanes x float2 = 128 floats
__global__ void k_spmm(const float* __restrict__ emb, float* __restrict__ out,
                       const float* __restrict__ val,
                       const int* __restrict__ row, const int* __restrict__ col) {
    int lane = threadIdx.x & 63;
    int wave = (int)((blockIdx.x * blockDim.x + threadIdx.x) >> 6);
    int nwaves = (int)((gridDim.x * blockDim.x) >> 6);
    for (int e = wave; e < NEDGES; e += nwaves) {
        int r = row[e];
        int c = col[e];
        float v = val[e];
        const float2 s = *(const float2*)(&emb[(size_t)c * D + lane * 2]);
        float* dst = &out[(size_t)r * D + lane * 2];
        atomicAdd(dst, v * s.x);
        atomicAdd(dst + 1, v * s.y);
    }
}

// gather selected rows from src and set/add into acc_sel [2*NSEL][D]
__global__ void k_sel(const float* __restrict__ src,
                      const int* __restrict__ users, const int* __restrict__ items,
                      float* __restrict__ acc, int add) {
    int idx = blockIdx.x * blockDim.x + threadIdx.x;
    if (idx >= 2 * NSEL * D) return;
    int r = idx >> 7;
    int d = idx & (D - 1);
    size_t node = (r < NSEL) ? (size_t)users[r] : (size_t)NUSERS + (size_t)items[r - NSEL];
    float v = src[node * D + d];
    if (add) acc[idx] += v;
    else     acc[idx] = v;
}

// one wave per output: gamma[i] = dot(accU[i], accI[i]) / 16
__global__ void k_dot(const float* __restrict__ acc, float* __restrict__ out) {
    int lane = threadIdx.x & 63;
    int w = (int)((blockIdx.x * blockDim.x + threadIdx.x) >> 6);
    if (w >= NSEL) return;
    const float* u = &acc[(size_t)w * D];
    const float* it = &acc[(size_t)(NSEL + w) * D];
    float s = u[lane] * it[lane] + u[lane + 64] * it[lane + 64];
    #pragma unroll
    for (int off = 32; off; off >>= 1) s += __shfl_down(s, off);
    if (lane == 0) out[w] = s * (1.0f / 16.0f);
}

extern "C" void kernel_launch(void* const* d_in, const int* in_sizes, int n_in,
                              void* d_out, int out_size, void* d_ws, size_t ws_size,
                              hipStream_t stream) {
    const float* user_emb = (const float*)d_in[0];
    const float* item_emb = (const float*)d_in[1];
    const float* edge_val = (const float*)d_in[2];
    const int*   edge_row = (const int*)d_in[3];
    const int*   edge_col = (const int*)d_in[4];
    const int*   users    = (const int*)d_in[5];
    const int*   items    = (const int*)d_in[6];
    float* out = (float*)d_out;

    const size_t tab = (size_t)NNODES * D;            // 19.2M floats
    float* bufA = (float*)d_ws;
    float* bufB = bufA + tab;
    float* accs = bufB + tab;                          // 2*NSEL*D floats

    k_init<<<2048, 256, 0, stream>>>((const float4*)user_emb, (const float4*)item_emb,
                                     (float4*)bufA);
    k_sel<<<(2 * NSEL * D) / 256, 256, 0, stream>>>(bufA, users, items, accs, 0);

    float* cur = bufA;
    float* nxt = bufB;
    for (int l = 0; l < NLAYERS; ++l) {
        k_zero<<<2048, 256, 0, stream>>>((float4*)nxt, tab / 4);
        k_spmm<<<4096, 256, 0, stream>>>(cur, nxt, edge_val, edge_row, edge_col);
        k_sel<<<(2 * NSEL * D) / 256, 256, 0, stream>>>(nxt, users, items, accs, 1);
        float* t = cur; cur = nxt; nxt = t;
    }
    k_dot<<<512, 256, 0, stream>>>(accs, out);
}

// Round 2
// 1449.837 us; speedup vs baseline: 5.4159x; 5.4159x over previous
//
#include <hip/hip_runtime.h>

#define D 128
#define NUSERS 100000
#define NITEMS 50000
#define NNODES 150000
#define NEDGES 3200000
#define NSEL 2048
#define NLAYERS 3
#define SCAN_T 1024

// cur = concat(user_emb, item_emb), float4-vectorized grid-stride copy
__global__ void k_init(const float4* __restrict__ u4, const float4* __restrict__ i4,
                       float4* __restrict__ cur) {
    size_t total = (size_t)NNODES * D / 4;
    size_t ubound = (size_t)NUSERS * D / 4;
    size_t stride = (size_t)gridDim.x * blockDim.x;
    for (size_t i = (size_t)blockIdx.x * blockDim.x + threadIdx.x; i < total; i += stride)
        cur[i] = (i < ubound) ? u4[i] : i4[i - ubound];
}

__global__ void k_zero_int(int* __restrict__ p, int n) {
    int stride = gridDim.x * blockDim.x;
    for (int i = blockIdx.x * blockDim.x + threadIdx.x; i < n; i += stride) p[i] = 0;
}

// histogram of edge rows
__global__ void k_count(const int* __restrict__ row, int* __restrict__ counts) {
    int stride = gridDim.x * blockDim.x;
    for (int e = blockIdx.x * blockDim.x + threadIdx.x; e < NEDGES; e += stride)
        atomicAdd(&counts[row[e]], 1);
}

// single-block exclusive scan of counts -> row_start (+ cursor copy)
__global__ void k_scan(const int* __restrict__ counts, int* __restrict__ row_start,
                       int* __restrict__ cursor) {
    __shared__ int sums[SCAN_T];
    int t = threadIdx.x;
    const int per = (NNODES + SCAN_T - 1) / SCAN_T;
    int base = t * per;
    int s = 0;
    for (int i = 0; i < per; ++i) {
        int idx = base + i;
        if (idx < NNODES) s += counts[idx];
    }
    sums[t] = s;
    __syncthreads();
    if (t == 0) {
        int run = 0;
        for (int i = 0; i < SCAN_T; ++i) { int v = sums[i]; sums[i] = run; run += v; }
    }
    __syncthreads();
    int off = sums[t];
    for (int i = 0; i < per; ++i) {
        int idx = base + i;
        if (idx < NNODES) {
            row_start[idx] = off;
            cursor[idx] = off;
            off += counts[idx];
        }
    }
    if (t == 0) row_start[NNODES] = NEDGES;
}

// scatter edges into row-sorted order
__global__ void k_scatter(const int* __restrict__ row, const int* __restrict__ col,
                          const float* __restrict__ val, int* __restrict__ cursor,
                          int* __restrict__ scols, float* __restrict__ svals) {
    int stride = gridDim.x * blockDim.x;
    for (int e = blockIdx.x * blockDim.x + threadIdx.x; e < NEDGES; e += stride) {
        int r = row[e];
        int pos = atomicAdd(&cursor[r], 1);
        scols[pos] = col[e];
        svals[pos] = val[e];
    }
}

// CSR SpMM: one wave per row, register accumulation, single non-atomic write
__global__ void k_spmm_csr(const float* __restrict__ emb, float* __restrict__ outp,
                           const int* __restrict__ row_start,
                           const int* __restrict__ scols, const float* __restrict__ svals) {
    int lane = threadIdx.x & 63;
    int w = (int)((blockIdx.x * blockDim.x + threadIdx.x) >> 6);
    if (w >= NNODES) return;
    int beg = __builtin_amdgcn_readfirstlane(row_start[w]);
    int end = __builtin_amdgcn_readfirstlane(row_start[w + 1]);
    float ax = 0.f, ay = 0.f;
    int e = beg;
    for (; e + 1 < end; e += 2) {
        int c0 = scols[e], c1 = scols[e + 1];
        float v0 = svals[e], v1 = svals[e + 1];
        const float2 s0 = *(const float2*)(&emb[(size_t)c0 * D + lane * 2]);
        const float2 s1 = *(const float2*)(&emb[(size_t)c1 * D + lane * 2]);
        ax += v0 * s0.x + v1 * s1.x;
        ay += v0 * s0.y + v1 * s1.y;
    }
    if (e < end) {
        int c = scols[e];
        float v = svals[e];
        const float2 s = *(const float2*)(&emb[(size_t)c * D + lane * 2]);
        ax += v * s.x;
        ay += v * s.y;
    }
    float2 r; r.x = ax; r.y = ay;
    *(float2*)(&outp[(size_t)w * D + lane * 2]) = r;
}

// gather selected rows from src and set/add into acc_sel [2*NSEL][D]
__global__ void k_sel(const float* __restrict__ src,
                      const int* __restrict__ users, const int* __restrict__ items,
                      float* __restrict__ acc, int add) {
    int idx = blockIdx.x * blockDim.x + threadIdx.x;
    if (idx >= 2 * NSEL * D) return;
    int r = idx >> 7;
    int d = idx & (D - 1);
    size_t node = (r < NSEL) ? (size_t)users[r] : (size_t)NUSERS + (size_t)items[r - NSEL];
    float v = src[node * D + d];
    if (add) acc[idx] += v;
    else     acc[idx] = v;
}

// one wave per output: gamma[i] = dot(accU[i], accI[i]) / 16
__global__ void k_dot(const float* __restrict__ acc, float* __restrict__ out) {
    int lane = threadIdx.x & 63;
    int w = (int)((blockIdx.x * blockDim.x + threadIdx.x) >> 6);
    if (w >= NSEL) return;
    const float* u = &acc[(size_t)w * D];
    const float* it = &acc[(size_t)(NSEL + w) * D];
    float s = u[lane] * it[lane] + u[lane + 64] * it[lane + 64];
    #pragma unroll
    for (int off = 32; off; off >>= 1) s += __shfl_down(s, off);
    if (lane == 0) out[w] = s * (1.0f / 16.0f);
}

extern "C" void kernel_launch(void* const* d_in, const int* in_sizes, int n_in,
                              void* d_out, int out_size, void* d_ws, size_t ws_size,
                              hipStream_t stream) {
    const float* user_emb = (const float*)d_in[0];
    const float* item_emb = (const float*)d_in[1];
    const float* edge_val = (const float*)d_in[2];
    const int*   edge_row = (const int*)d_in[3];
    const int*   edge_col = (const int*)d_in[4];
    const int*   users    = (const int*)d_in[5];
    const int*   items    = (const int*)d_in[6];
    float* out = (float*)d_out;

    const size_t tab = (size_t)NNODES * D;            // 19.2M floats
    float* bufA      = (float*)d_ws;                  // 76.8 MB
    float* bufB      = bufA + tab;                    // 76.8 MB
    float* accs      = bufB + tab;                    // 2 MB
    float* svals     = accs + (size_t)2 * NSEL * D;   // 12.8 MB
    int*   scols     = (int*)(svals + NEDGES);        // 12.8 MB
    int*   counts    = scols + NEDGES;                // 600 KB
    int*   row_start = counts + NNODES;               // 600 KB
    int*   cursor    = row_start + NNODES + 1;        // 600 KB

    // ---- build CSR (counting sort by row) ----
    k_zero_int<<<256, 256, 0, stream>>>(counts, NNODES);
    k_count<<<4096, 256, 0, stream>>>(edge_row, counts);
    k_scan<<<1, SCAN_T, 0, stream>>>(counts, row_start, cursor);
    k_scatter<<<4096, 256, 0, stream>>>(edge_row, edge_col, edge_val, cursor, scols, svals);

    // ---- embeddings ----
    k_init<<<2048, 256, 0, stream>>>((const float4*)user_emb, (const float4*)item_emb,
                                     (float4*)bufA);
    k_sel<<<(2 * NSEL * D) / 256, 256, 0, stream>>>(bufA, users, items, accs, 0);

    float* cur = bufA;
    float* nxt = bufB;
    for (int l = 0; l < NLAYERS; ++l) {
        k_spmm_csr<<<(NNODES + 3) / 4, 256, 0, stream>>>(cur, nxt, row_start, scols, svals);
        k_sel<<<(2 * NSEL * D) / 256, 256, 0, stream>>>(nxt, users, items, accs, 1);
        float* t = cur; cur = nxt; nxt = t;
    }
    k_dot<<<512, 256, 0, stream>>>(accs, out);
}

// Round 3
// 855.610 us; speedup vs baseline: 9.1772x; 1.6945x over previous
//
#include <hip/hip_runtime.h>

#define D 128
#define NUSERS 100000
#define NITEMS 50000
#define NNODES 150000
#define NEDGES 3200000
#define NSEL 2048
#define NLAYERS 3
#define NB ((NNODES + 255) / 256)   // 586 scan blocks

// cur = concat(user_emb, item_emb), float4-vectorized grid-stride copy
__global__ void k_init(const float4* __restrict__ u4, const float4* __restrict__ i4,
                       float4* __restrict__ cur) {
    size_t total = (size_t)NNODES * D / 4;
    size_t ubound = (size_t)NUSERS * D / 4;
    size_t stride = (size_t)gridDim.x * blockDim.x;
    for (size_t i = (size_t)blockIdx.x * blockDim.x + threadIdx.x; i < total; i += stride)
        cur[i] = (i < ubound) ? u4[i] : i4[i - ubound];
}

__global__ void k_zero_int(int* __restrict__ p, int n) {
    int stride = gridDim.x * blockDim.x;
    for (int i = blockIdx.x * blockDim.x + threadIdx.x; i < n; i += stride) p[i] = 0;
}

// histogram of edge rows
__global__ void k_count(const int* __restrict__ row, int* __restrict__ counts) {
    int stride = gridDim.x * blockDim.x;
    for (int e = blockIdx.x * blockDim.x + threadIdx.x; e < NEDGES; e += stride)
        atomicAdd(&counts[row[e]], 1);
}

// ---- parallel 3-pass exclusive scan of counts[NNODES] ----
__device__ inline int block_excl_scan(int v, int* lds, int nw) {
    int lane = threadIdx.x & 63;
    int wid = (int)(threadIdx.x >> 6);
    int x = v;
    #pragma unroll
    for (int off = 1; off < 64; off <<= 1) {
        int y = __shfl_up(x, off);
        if (lane >= off) x += y;
    }
    if (lane == 63) lds[wid] = x;        // wave inclusive total
    __syncthreads();
    if (wid == 0) {
        int s = (lane < nw) ? lds[lane] : 0;
        #pragma unroll
        for (int off = 1; off < 16; off <<= 1) {
            int y = __shfl_up(s, off);
            if (lane >= off) s += y;
        }
        if (lane < nw) lds[lane] = s;    // inclusive scan of wave totals
    }
    __syncthreads();
    int waveoff = (wid == 0) ? 0 : lds[wid - 1];
    return waveoff + x - v;              // exclusive
}

__global__ void k_blocksum(const int* __restrict__ counts, int* __restrict__ bsums) {
    int i = blockIdx.x * 256 + threadIdx.x;
    int v = (i < NNODES) ? counts[i] : 0;
    #pragma unroll
    for (int off = 32; off; off >>= 1) v += __shfl_down(v, off);
    __shared__ int lds[4];
    int lane = threadIdx.x & 63, wid = (int)(threadIdx.x >> 6);
    if (lane == 0) lds[wid] = v;
    __syncthreads();
    if (threadIdx.x == 0) bsums[blockIdx.x] = lds[0] + lds[1] + lds[2] + lds[3];
}

__global__ void k_scanbsums(int* __restrict__ bsums) {
    __shared__ int lds[16];
    int t = threadIdx.x;
    int v = (t < NB) ? bsums[t] : 0;
    int ex = block_excl_scan(v, lds, 16);
    if (t < NB) bsums[t] = ex;
}

__global__ void k_scanfinal(const int* __restrict__ counts, const int* __restrict__ bsums,
                            int* __restrict__ row_start, int* __restrict__ cursor) {
    __shared__ int lds[4];
    int i = blockIdx.x * 256 + threadIdx.x;
    int v = (i < NNODES) ? counts[i] : 0;
    int ex = block_excl_scan(v, lds, 4);
    int off = bsums[blockIdx.x] + ex;
    if (i < NNODES) { row_start[i] = off; cursor[i] = off; }
    if (i == NNODES) row_start[NNODES] = NEDGES;
}

// scatter edges into row-sorted order
__global__ void k_scatter(const int* __restrict__ row, const int* __restrict__ col,
                          const float* __restrict__ val, int* __restrict__ cursor,
                          int* __restrict__ scols, float* __restrict__ svals) {
    int stride = gridDim.x * blockDim.x;
    for (int e = blockIdx.x * blockDim.x + threadIdx.x; e < NEDGES; e += stride) {
        int r = row[e];
        int pos = atomicAdd(&cursor[r], 1);
        scols[pos] = col[e];
        svals[pos] = val[e];
    }
}

// CSR SpMM: one wave per row, register accumulation, single non-atomic write
__global__ void k_spmm_csr(const float* __restrict__ emb, float* __restrict__ outp,
                           const int* __restrict__ row_start,
                           const int* __restrict__ scols, const float* __restrict__ svals) {
    int lane = threadIdx.x & 63;
    int w = (int)((blockIdx.x * blockDim.x + threadIdx.x) >> 6);
    if (w >= NNODES) return;
    int beg = __builtin_amdgcn_readfirstlane(row_start[w]);
    int end = __builtin_amdgcn_readfirstlane(row_start[w + 1]);
    float ax = 0.f, ay = 0.f;
    int e = beg;
    for (; e + 1 < end; e += 2) {
        int c0 = scols[e], c1 = scols[e + 1];
        float v0 = svals[e], v1 = svals[e + 1];
        const float2 s0 = *(const float2*)(&emb[(size_t)c0 * D + lane * 2]);
        const float2 s1 = *(const float2*)(&emb[(size_t)c1 * D + lane * 2]);
        ax += v0 * s0.x + v1 * s1.x;
        ay += v0 * s0.y + v1 * s1.y;
    }
    if (e < end) {
        int c = scols[e];
        float v = svals[e];
        const float2 s = *(const float2*)(&emb[(size_t)c * D + lane * 2]);
        ax += v * s.x;
        ay += v * s.y;
    }
    float2 r; r.x = ax; r.y = ay;
    *(float2*)(&outp[(size_t)w * D + lane * 2]) = r;
}

// layer-3 SpMM at selected rows only, accumulating directly into acc_sel
__global__ void k_spmm_sel(const float* __restrict__ emb,
                           const int* __restrict__ users, const int* __restrict__ items,
                           const int* __restrict__ row_start,
                           const int* __restrict__ scols, const float* __restrict__ svals,
                           float* __restrict__ acc) {
    int lane = threadIdx.x & 63;
    int w = (int)((blockIdx.x * blockDim.x + threadIdx.x) >> 6);
    if (w >= 2 * NSEL) return;
    int node = (w < NSEL) ? users[w] : NUSERS + items[w - NSEL];
    int beg = __builtin_amdgcn_readfirstlane(row_start[node]);
    int end = __builtin_amdgcn_readfirstlane(row_start[node + 1]);
    float ax = 0.f, ay = 0.f;
    for (int e = beg; e < end; ++e) {
        int c = scols[e];
        float v = svals[e];
        const float2 s = *(const float2*)(&emb[(size_t)c * D + lane * 2]);
        ax += v * s.x;
        ay += v * s.y;
    }
    float2* p = (float2*)&acc[(size_t)w * D + lane * 2];
    float2 r = *p;
    r.x += ax; r.y += ay;
    *p = r;
}

// gather selected rows from src and set/add into acc_sel [2*NSEL][D]
__global__ void k_sel(const float* __restrict__ src,
                      const int* __restrict__ users, const int* __restrict__ items,
                      float* __restrict__ acc, int add) {
    int idx = blockIdx.x * blockDim.x + threadIdx.x;
    if (idx >= 2 * NSEL * D) return;
    int r = idx >> 7;
    int d = idx & (D - 1);
    size_t node = (r < NSEL) ? (size_t)users[r] : (size_t)NUSERS + (size_t)items[r - NSEL];
    float v = src[node * D + d];
    if (add) acc[idx] += v;
    else     acc[idx] = v;
}

// one wave per output: gamma[i] = dot(accU[i], accI[i]) / 16
__global__ void k_dot(const float* __restrict__ acc, float* __restrict__ out) {
    int lane = threadIdx.x & 63;
    int w = (int)((blockIdx.x * blockDim.x + threadIdx.x) >> 6);
    if (w >= NSEL) return;
    const float* u = &acc[(size_t)w * D];
    const float* it = &acc[(size_t)(NSEL + w) * D];
    float s = u[lane] * it[lane] + u[lane + 64] * it[lane + 64];
    #pragma unroll
    for (int off = 32; off; off >>= 1) s += __shfl_down(s, off);
    if (lane == 0) out[w] = s * (1.0f / 16.0f);
}

extern "C" void kernel_launch(void* const* d_in, const int* in_sizes, int n_in,
                              void* d_out, int out_size, void* d_ws, size_t ws_size,
                              hipStream_t stream) {
    const float* user_emb = (const float*)d_in[0];
    const float* item_emb = (const float*)d_in[1];
    const float* edge_val = (const float*)d_in[2];
    const int*   edge_row = (const int*)d_in[3];
    const int*   edge_col = (const int*)d_in[4];
    const int*   users    = (const int*)d_in[5];
    const int*   items    = (const int*)d_in[6];
    float* out = (float*)d_out;

    const size_t tab = (size_t)NNODES * D;            // 19.2M floats
    float* bufA      = (float*)d_ws;                  // 76.8 MB
    float* bufB      = bufA + tab;                    // 76.8 MB
    float* accs      = bufB + tab;                    // 2 MB
    float* svals     = accs + (size_t)2 * NSEL * D;   // 12.8 MB
    int*   scols     = (int*)(svals + NEDGES);        // 12.8 MB
    int*   counts    = scols + NEDGES;                // 600 KB
    int*   row_start = counts + NNODES;               // 600 KB
    int*   cursor    = row_start + NNODES + 1;        // 600 KB
    int*   bsums     = cursor + NNODES;               // 2.4 KB

    // ---- build CSR (counting sort by row) ----
    k_zero_int<<<256, 256, 0, stream>>>(counts, NNODES);
    k_count<<<4096, 256, 0, stream>>>(edge_row, counts);
    k_blocksum<<<NB, 256, 0, stream>>>(counts, bsums);
    k_scanbsums<<<1, 1024, 0, stream>>>(bsums);
    k_scanfinal<<<NB, 256, 0, stream>>>(counts, bsums, row_start, cursor);
    k_scatter<<<4096, 256, 0, stream>>>(edge_row, edge_col, edge_val, cursor, scols, svals);

    // ---- embeddings ----
    k_init<<<2048, 256, 0, stream>>>((const float4*)user_emb, (const float4*)item_emb,
                                     (float4*)bufA);
    k_sel<<<(2 * NSEL * D) / 256, 256, 0, stream>>>(bufA, users, items, accs, 0);

    // layer 1: full
    k_spmm_csr<<<(NNODES + 3) / 4, 256, 0, stream>>>(bufA, bufB, row_start, scols, svals);
    k_sel<<<(2 * NSEL * D) / 256, 256, 0, stream>>>(bufB, users, items, accs, 1);
    // layer 2: full
    k_spmm_csr<<<(NNODES + 3) / 4, 256, 0, stream>>>(bufB, bufA, row_start, scols, svals);
    k_sel<<<(2 * NSEL * D) / 256, 256, 0, stream>>>(bufA, users, items, accs, 1);
    // layer 3: selected rows only, straight into acc
    k_spmm_sel<<<(2 * NSEL) / 4, 256, 0, stream>>>(bufA, users, items, row_start,
                                                   scols, svals, accs);

    k_dot<<<512, 256, 0, stream>>>(accs, out);
}

// Round 4
// 834.347 us; speedup vs baseline: 9.4111x; 1.0255x over previous
//
#include <hip/hip_runtime.h>

#define D 128
#define NUSERS 100000
#define NITEMS 50000
#define NNODES 150000
#define NEDGES 3200000
#define NSEL 2048
#define NB ((NNODES + 255) / 256)   // 586 scan blocks
#define NPASS 8
#define ROWS_PER_PASS (NNODES / NPASS)  // 18750

// cur = concat(user_emb, item_emb), float4-vectorized grid-stride copy
__global__ void k_init(const float4* __restrict__ u4, const float4* __restrict__ i4,
                       float4* __restrict__ cur) {
    size_t total = (size_t)NNODES * D / 4;
    size_t ubound = (size_t)NUSERS * D / 4;
    size_t stride = (size_t)gridDim.x * blockDim.x;
    for (size_t i = (size_t)blockIdx.x * blockDim.x + threadIdx.x; i < total; i += stride)
        cur[i] = (i < ubound) ? u4[i] : i4[i - ubound];
}

__global__ void k_zero_int(int* __restrict__ p, int n) {
    int stride = gridDim.x * blockDim.x;
    for (int i = blockIdx.x * blockDim.x + threadIdx.x; i < n; i += stride) p[i] = 0;
}

// histogram of edge rows
__global__ void k_count(const int* __restrict__ row, int* __restrict__ counts) {
    int stride = gridDim.x * blockDim.x;
    for (int e = blockIdx.x * blockDim.x + threadIdx.x; e < NEDGES; e += stride)
        atomicAdd(&counts[row[e]], 1);
}

// ---- parallel 3-pass exclusive scan of counts[NNODES] ----
__device__ inline int block_excl_scan(int v, int* lds, int nw) {
    int lane = threadIdx.x & 63;
    int wid = (int)(threadIdx.x >> 6);
    int x = v;
    #pragma unroll
    for (int off = 1; off < 64; off <<= 1) {
        int y = __shfl_up(x, off);
        if (lane >= off) x += y;
    }
    if (lane == 63) lds[wid] = x;        // wave inclusive total
    __syncthreads();
    if (wid == 0) {
        int s = (lane < nw) ? lds[lane] : 0;
        #pragma unroll
        for (int off = 1; off < 16; off <<= 1) {
            int y = __shfl_up(s, off);
            if (lane >= off) s += y;
        }
        if (lane < nw) lds[lane] = s;    // inclusive scan of wave totals
    }
    __syncthreads();
    int waveoff = (wid == 0) ? 0 : lds[wid - 1];
    return waveoff + x - v;              // exclusive
}

__global__ void k_blocksum(const int* __restrict__ counts, int* __restrict__ bsums) {
    int i = blockIdx.x * 256 + threadIdx.x;
    int v = (i < NNODES) ? counts[i] : 0;
    #pragma unroll
    for (int off = 32; off; off >>= 1) v += __shfl_down(v, off);
    __shared__ int lds[4];
    int lane = threadIdx.x & 63, wid = (int)(threadIdx.x >> 6);
    if (lane == 0) lds[wid] = v;
    __syncthreads();
    if (threadIdx.x == 0) bsums[blockIdx.x] = lds[0] + lds[1] + lds[2] + lds[3];
}

__global__ void k_scanbsums(int* __restrict__ bsums) {
    __shared__ int lds[16];
    int t = threadIdx.x;
    int v = (t < NB) ? bsums[t] : 0;
    int ex = block_excl_scan(v, lds, 16);
    if (t < NB) bsums[t] = ex;
}

__global__ void k_scanfinal(const int* __restrict__ counts, const int* __restrict__ bsums,
                            int* __restrict__ row_start, int* __restrict__ cursor) {
    __shared__ int lds[4];
    int i = blockIdx.x * 256 + threadIdx.x;
    int v = (i < NNODES) ? counts[i] : 0;
    int ex = block_excl_scan(v, lds, 4);
    int off = bsums[blockIdx.x] + ex;
    if (i < NNODES) { row_start[i] = off; cursor[i] = off; }
    if (i == NNODES) row_start[NNODES] = NEDGES;
}

// windowed scatter: only edges with row in [lo, lo+ROWS_PER_PASS) — their
// destinations span a contiguous ~3.2MB window of recs, L2-resident for the pass
__global__ void k_scatter_pass(const int* __restrict__ row, const int* __restrict__ col,
                               const float* __restrict__ val, int* __restrict__ cursor,
                               int2* __restrict__ recs, int lo) {
    int stride = gridDim.x * blockDim.x;
    int hi = lo + ROWS_PER_PASS;
    for (int e = blockIdx.x * blockDim.x + threadIdx.x; e < NEDGES; e += stride) {
        int r = row[e];
        if (r < lo || r >= hi) continue;
        int pos = atomicAdd(&cursor[r], 1);
        int2 rc;
        rc.x = col[e];
        rc.y = __float_as_int(val[e]);
        recs[pos] = rc;
    }
}

// CSR SpMM: one wave per row, register accumulation, single non-atomic write
__global__ void k_spmm_csr(const float* __restrict__ emb, float* __restrict__ outp,
                           const int* __restrict__ row_start,
                           const int2* __restrict__ recs) {
    int lane = threadIdx.x & 63;
    int w = (int)((blockIdx.x * blockDim.x + threadIdx.x) >> 6);
    if (w >= NNODES) return;
    int beg = __builtin_amdgcn_readfirstlane(row_start[w]);
    int end = __builtin_amdgcn_readfirstlane(row_start[w + 1]);
    float ax = 0.f, ay = 0.f;
    int e = beg;
    for (; e + 1 < end; e += 2) {
        int2 r0 = recs[e], r1 = recs[e + 1];
        float v0 = __int_as_float(r0.y), v1 = __int_as_float(r1.y);
        const float2 s0 = *(const float2*)(&emb[(size_t)r0.x * D + lane * 2]);
        const float2 s1 = *(const float2*)(&emb[(size_t)r1.x * D + lane * 2]);
        ax += v0 * s0.x + v1 * s1.x;
        ay += v0 * s0.y + v1 * s1.y;
    }
    if (e < end) {
        int2 r0 = recs[e];
        float v = __int_as_float(r0.y);
        const float2 s = *(const float2*)(&emb[(size_t)r0.x * D + lane * 2]);
        ax += v * s.x;
        ay += v * s.y;
    }
    float2 r; r.x = ax; r.y = ay;
    *(float2*)(&outp[(size_t)w * D + lane * 2]) = r;
}

// layer-3 SpMM at selected rows only, fused with acc += emb[node] (the k_sel step)
__global__ void k_spmm_sel(const float* __restrict__ emb,
                           const int* __restrict__ users, const int* __restrict__ items,
                           const int* __restrict__ row_start,
                           const int2* __restrict__ recs,
                           float* __restrict__ acc) {
    int lane = threadIdx.x & 63;
    int w = (int)((blockIdx.x * blockDim.x + threadIdx.x) >> 6);
    if (w >= 2 * NSEL) return;
    int node = (w < NSEL) ? users[w] : NUSERS + items[w - NSEL];
    int beg = __builtin_amdgcn_readfirstlane(row_start[node]);
    int end = __builtin_amdgcn_readfirstlane(row_start[node + 1]);
    // acc += emb[node] (layer-2 contribution) + sum_e val*emb[col] (layer-3)
    const float2 e2 = *(const float2*)(&emb[(size_t)node * D + lane * 2]);
    float ax = e2.x, ay = e2.y;
    for (int e = beg; e < end; ++e) {
        int2 r0 = recs[e];
        float v = __int_as_float(r0.y);
        const float2 s = *(const float2*)(&emb[(size_t)r0.x * D + lane * 2]);
        ax += v * s.x;
        ay += v * s.y;
    }
    float2* p = (float2*)&acc[(size_t)w * D + lane * 2];
    float2 r = *p;
    r.x += ax; r.y += ay;
    *p = r;
}

// gather selected rows from src and set/add into acc_sel [2*NSEL][D]
__global__ void k_sel(const float* __restrict__ src,
                      const int* __restrict__ users, const int* __restrict__ items,
                      float* __restrict__ acc, int add) {
    int idx = blockIdx.x * blockDim.x + threadIdx.x;
    if (idx >= 2 * NSEL * D) return;
    int r = idx >> 7;
    int d = idx & (D - 1);
    size_t node = (r < NSEL) ? (size_t)users[r] : (size_t)NUSERS + (size_t)items[r - NSEL];
    float v = src[node * D + d];
    if (add) acc[idx] += v;
    else     acc[idx] = v;
}

// one wave per output: gamma[i] = dot(accU[i], accI[i]) / 16
__global__ void k_dot(const float* __restrict__ acc, float* __restrict__ out) {
    int lane = threadIdx.x & 63;
    int w = (int)((blockIdx.x * blockDim.x + threadIdx.x) >> 6);
    if (w >= NSEL) return;
    const float* u = &acc[(size_t)w * D];
    const float* it = &acc[(size_t)(NSEL + w) * D];
    float s = u[lane] * it[lane] + u[lane + 64] * it[lane + 64];
    #pragma unroll
    for (int off = 32; off; off >>= 1) s += __shfl_down(s, off);
    if (lane == 0) out[w] = s * (1.0f / 16.0f);
}

extern "C" void kernel_launch(void* const* d_in, const int* in_sizes, int n_in,
                              void* d_out, int out_size, void* d_ws, size_t ws_size,
                              hipStream_t stream) {
    const float* user_emb = (const float*)d_in[0];
    const float* item_emb = (const float*)d_in[1];
    const float* edge_val = (const float*)d_in[2];
    const int*   edge_row = (const int*)d_in[3];
    const int*   edge_col = (const int*)d_in[4];
    const int*   users    = (const int*)d_in[5];
    const int*   items    = (const int*)d_in[6];
    float* out = (float*)d_out;

    const size_t tab = (size_t)NNODES * D;            // 19.2M floats
    float* bufA      = (float*)d_ws;                  // 76.8 MB
    float* bufB      = bufA + tab;                    // 76.8 MB
    float* accs      = bufB + tab;                    // 2 MB
    int2*  recs      = (int2*)(accs + (size_t)2 * NSEL * D);  // 25.6 MB
    int*   counts    = (int*)(recs + NEDGES);         // 600 KB
    int*   row_start = counts + NNODES;               // 600 KB
    int*   cursor    = row_start + NNODES + 1;        // 600 KB
    int*   bsums     = cursor + NNODES;               // 2.4 KB

    // ---- build CSR (counting sort by row, windowed scatter) ----
    k_zero_int<<<256, 256, 0, stream>>>(counts, NNODES);
    k_count<<<4096, 256, 0, stream>>>(edge_row, counts);
    k_blocksum<<<NB, 256, 0, stream>>>(counts, bsums);
    k_scanbsums<<<1, 1024, 0, stream>>>(bsums);
    k_scanfinal<<<NB, 256, 0, stream>>>(counts, bsums, row_start, cursor);
    for (int p = 0; p < NPASS; ++p)
        k_scatter_pass<<<2048, 256, 0, stream>>>(edge_row, edge_col, edge_val,
                                                 cursor, recs, p * ROWS_PER_PASS);

    // ---- embeddings ----
    k_init<<<2048, 256, 0, stream>>>((const float4*)user_emb, (const float4*)item_emb,
                                     (float4*)bufA);
    k_sel<<<(2 * NSEL * D) / 256, 256, 0, stream>>>(bufA, users, items, accs, 0);

    // layer 1: full
    k_spmm_csr<<<(NNODES + 3) / 4, 256, 0, stream>>>(bufA, bufB, row_start, recs);
    k_sel<<<(2 * NSEL * D) / 256, 256, 0, stream>>>(bufB, users, items, accs, 1);
    // layer 2: full
    k_spmm_csr<<<(NNODES + 3) / 4, 256, 0, stream>>>(bufB, bufA, row_start, recs);
    // layer 3 (selected rows only) fused with layer-2 k_sel
    k_spmm_sel<<<(2 * NSEL) / 4, 256, 0, stream>>>(bufA, users, items, row_start,
                                                   recs, accs);

    k_dot<<<512, 256, 0, stream>>>(accs, out);
}

// Round 5
// 580.356 us; speedup vs baseline: 13.5299x; 1.4376x over previous
//
#include <hip/hip_runtime.h>

#define D 128
#define NUSERS 100000
#define NITEMS 50000
#define NNODES 150000
#define NEDGES 3200000
#define NSEL 2048
#define NB ((NNODES + 255) / 256)   // 586 scan blocks
#define NPASS 4
#define ROWS_PER_PASS (NNODES / NPASS)  // 37500

typedef unsigned int uint_t;
typedef unsigned short ushort_t;

__device__ inline uint_t bf16_rne(float f) {
    uint_t x = __float_as_uint(f);
    return (x + 0x7FFFu + ((x >> 16) & 1u)) >> 16;
}

// cur(bf16) = concat(user_emb, item_emb); each thread converts 8 floats -> uint4
__global__ void k_init_bf16(const float4* __restrict__ u4, const float4* __restrict__ i4,
                            uint4* __restrict__ cur) {
    size_t total8 = (size_t)NNODES * D / 8;
    size_t ub8 = (size_t)NUSERS * D / 8;
    size_t stride = (size_t)gridDim.x * blockDim.x;
    for (size_t i = (size_t)blockIdx.x * blockDim.x + threadIdx.x; i < total8; i += stride) {
        const float4* src = (i < ub8) ? &u4[2 * i] : &i4[2 * (i - ub8)];
        float4 a = src[0], b = src[1];
        uint4 o;
        o.x = (bf16_rne(a.y) << 16) | bf16_rne(a.x);
        o.y = (bf16_rne(a.w) << 16) | bf16_rne(a.z);
        o.z = (bf16_rne(b.y) << 16) | bf16_rne(b.x);
        o.w = (bf16_rne(b.w) << 16) | bf16_rne(b.z);
        cur[i] = o;
    }
}

__global__ void k_zero_int(int* __restrict__ p, int n) {
    int stride = gridDim.x * blockDim.x;
    for (int i = blockIdx.x * blockDim.x + threadIdx.x; i < n; i += stride) p[i] = 0;
}

// histogram of edge rows
__global__ void k_count(const int* __restrict__ row, int* __restrict__ counts) {
    int stride = gridDim.x * blockDim.x;
    for (int e = blockIdx.x * blockDim.x + threadIdx.x; e < NEDGES; e += stride)
        atomicAdd(&counts[row[e]], 1);
}

// ---- parallel 3-pass exclusive scan of counts[NNODES] ----
__device__ inline int block_excl_scan(int v, int* lds, int nw) {
    int lane = threadIdx.x & 63;
    int wid = (int)(threadIdx.x >> 6);
    int x = v;
    #pragma unroll
    for (int off = 1; off < 64; off <<= 1) {
        int y = __shfl_up(x, off);
        if (lane >= off) x += y;
    }
    if (lane == 63) lds[wid] = x;
    __syncthreads();
    if (wid == 0) {
        int s = (lane < nw) ? lds[lane] : 0;
        #pragma unroll
        for (int off = 1; off < 16; off <<= 1) {
            int y = __shfl_up(s, off);
            if (lane >= off) s += y;
        }
        if (lane < nw) lds[lane] = s;
    }
    __syncthreads();
    int waveoff = (wid == 0) ? 0 : lds[wid - 1];
    return waveoff + x - v;
}

__global__ void k_blocksum(const int* __restrict__ counts, int* __restrict__ bsums) {
    int i = blockIdx.x * 256 + threadIdx.x;
    int v = (i < NNODES) ? counts[i] : 0;
    #pragma unroll
    for (int off = 32; off; off >>= 1) v += __shfl_down(v, off);
    __shared__ int lds[4];
    int lane = threadIdx.x & 63, wid = (int)(threadIdx.x >> 6);
    if (lane == 0) lds[wid] = v;
    __syncthreads();
    if (threadIdx.x == 0) bsums[blockIdx.x] = lds[0] + lds[1] + lds[2] + lds[3];
}

__global__ void k_scanbsums(int* __restrict__ bsums) {
    __shared__ int lds[16];
    int t = threadIdx.x;
    int v = (t < NB) ? bsums[t] : 0;
    int ex = block_excl_scan(v, lds, 16);
    if (t < NB) bsums[t] = ex;
}

__global__ void k_scanfinal(const int* __restrict__ counts, const int* __restrict__ bsums,
                            int* __restrict__ row_start, int* __restrict__ cursor) {
    __shared__ int lds[4];
    int i = blockIdx.x * 256 + threadIdx.x;
    int v = (i < NNODES) ? counts[i] : 0;
    int ex = block_excl_scan(v, lds, 4);
    int off = bsums[blockIdx.x] + ex;
    if (i < NNODES) { row_start[i] = off; cursor[i] = off; }
    if (i == NNODES) row_start[NNODES] = NEDGES;
}

// windowed scatter: only edges with row in [lo, lo+ROWS_PER_PASS)
__global__ void k_scatter_pass(const int* __restrict__ row, const int* __restrict__ col,
                               const float* __restrict__ val, int* __restrict__ cursor,
                               int2* __restrict__ recs, int lo) {
    int stride = gridDim.x * blockDim.x;
    int hi = lo + ROWS_PER_PASS;
    for (int e = blockIdx.x * blockDim.x + threadIdx.x; e < NEDGES; e += stride) {
        int r = row[e];
        if (r < lo || r >= hi) continue;
        int pos = atomicAdd(&cursor[r], 1);
        int2 rc;
        rc.x = col[e];
        rc.y = __float_as_int(val[e]);
        recs[pos] = rc;
    }
}

// CSR SpMM on bf16 table: one wave per row, lane handles 2 elems (one uint),
// f32 accumulate, RNE bf16 store
__global__ void k_spmm_csr(const uint_t* __restrict__ emb, uint_t* __restrict__ outp,
                           const int* __restrict__ row_start,
                           const int2* __restrict__ recs) {
    int lane = threadIdx.x & 63;
    int w = (int)((blockIdx.x * blockDim.x + threadIdx.x) >> 6);
    if (w >= NNODES) return;
    int beg = __builtin_amdgcn_readfirstlane(row_start[w]);
    int end = __builtin_amdgcn_readfirstlane(row_start[w + 1]);
    float ax = 0.f, ay = 0.f;
    int e = beg;
    for (; e + 3 < end; e += 4) {
        int2 r0 = recs[e], r1 = recs[e + 1], r2 = recs[e + 2], r3 = recs[e + 3];
        uint_t g0 = emb[(size_t)r0.x * 64 + lane];
        uint_t g1 = emb[(size_t)r1.x * 64 + lane];
        uint_t g2 = emb[(size_t)r2.x * 64 + lane];
        uint_t g3 = emb[(size_t)r3.x * 64 + lane];
        float v0 = __int_as_float(r0.y), v1 = __int_as_float(r1.y);
        float v2 = __int_as_float(r2.y), v3 = __int_as_float(r3.y);
        ax += v0 * __uint_as_float(g0 << 16) + v1 * __uint_as_float(g1 << 16)
            + v2 * __uint_as_float(g2 << 16) + v3 * __uint_as_float(g3 << 16);
        ay += v0 * __uint_as_float(g0 & 0xFFFF0000u) + v1 * __uint_as_float(g1 & 0xFFFF0000u)
            + v2 * __uint_as_float(g2 & 0xFFFF0000u) + v3 * __uint_as_float(g3 & 0xFFFF0000u);
    }
    for (; e < end; ++e) {
        int2 r0 = recs[e];
        float v = __int_as_float(r0.y);
        uint_t g = emb[(size_t)r0.x * 64 + lane];
        ax += v * __uint_as_float(g << 16);
        ay += v * __uint_as_float(g & 0xFFFF0000u);
    }
    outp[(size_t)w * 64 + lane] = (bf16_rne(ay) << 16) | bf16_rne(ax);
}

// layer-3 SpMM at selected rows only, fused with acc += emb[node]
__global__ void k_spmm_sel(const uint_t* __restrict__ emb,
                           const int* __restrict__ users, const int* __restrict__ items,
                           const int* __restrict__ row_start,
                           const int2* __restrict__ recs,
                           float* __restrict__ acc) {
    int lane = threadIdx.x & 63;
    int w = (int)((blockIdx.x * blockDim.x + threadIdx.x) >> 6);
    if (w >= 2 * NSEL) return;
    int node = (w < NSEL) ? users[w] : NUSERS + items[w - NSEL];
    int beg = __builtin_amdgcn_readfirstlane(row_start[node]);
    int end = __builtin_amdgcn_readfirstlane(row_start[node + 1]);
    uint_t e2 = emb[(size_t)node * 64 + lane];
    float ax = __uint_as_float(e2 << 16);
    float ay = __uint_as_float(e2 & 0xFFFF0000u);
    for (int e = beg; e < end; ++e) {
        int2 r0 = recs[e];
        float v = __int_as_float(r0.y);
        uint_t g = emb[(size_t)r0.x * 64 + lane];
        ax += v * __uint_as_float(g << 16);
        ay += v * __uint_as_float(g & 0xFFFF0000u);
    }
    float2* p = (float2*)&acc[(size_t)w * D + lane * 2];
    float2 r = *p;
    r.x += ax; r.y += ay;
    *p = r;
}

// layer-0 gather from the f32 inputs (set mode)
__global__ void k_sel0(const float* __restrict__ user_emb, const float* __restrict__ item_emb,
                       const int* __restrict__ users, const int* __restrict__ items,
                       float* __restrict__ acc) {
    int idx = blockIdx.x * blockDim.x + threadIdx.x;
    if (idx >= 2 * NSEL * D) return;
    int r = idx >> 7;
    int d = idx & (D - 1);
    const float* src = (r < NSEL) ? &user_emb[(size_t)users[r] * D]
                                  : &item_emb[(size_t)items[r - NSEL] * D];
    acc[idx] = src[d];
}

// gather selected rows from bf16 table, add into acc
__global__ void k_sel_bf16(const ushort_t* __restrict__ src,
                           const int* __restrict__ users, const int* __restrict__ items,
                           float* __restrict__ acc) {
    int idx = blockIdx.x * blockDim.x + threadIdx.x;
    if (idx >= 2 * NSEL * D) return;
    int r = idx >> 7;
    int d = idx & (D - 1);
    size_t node = (r < NSEL) ? (size_t)users[r] : (size_t)NUSERS + (size_t)items[r - NSEL];
    uint_t u = (uint_t)src[node * D + d] << 16;
    acc[idx] += __uint_as_float(u);
}

// one wave per output: gamma[i] = dot(accU[i], accI[i]) / 16
__global__ void k_dot(const float* __restrict__ acc, float* __restrict__ out) {
    int lane = threadIdx.x & 63;
    int w = (int)((blockIdx.x * blockDim.x + threadIdx.x) >> 6);
    if (w >= NSEL) return;
    const float* u = &acc[(size_t)w * D];
    const float* it = &acc[(size_t)(NSEL + w) * D];
    float s = u[lane] * it[lane] + u[lane + 64] * it[lane + 64];
    #pragma unroll
    for (int off = 32; off; off >>= 1) s += __shfl_down(s, off);
    if (lane == 0) out[w] = s * (1.0f / 16.0f);
}

extern "C" void kernel_launch(void* const* d_in, const int* in_sizes, int n_in,
                              void* d_out, int out_size, void* d_ws, size_t ws_size,
                              hipStream_t stream) {
    const float* user_emb = (const float*)d_in[0];
    const float* item_emb = (const float*)d_in[1];
    const float* edge_val = (const float*)d_in[2];
    const int*   edge_row = (const int*)d_in[3];
    const int*   edge_col = (const int*)d_in[4];
    const int*   users    = (const int*)d_in[5];
    const int*   items    = (const int*)d_in[6];
    float* out = (float*)d_out;

    const size_t tab = (size_t)NNODES * D;                 // elements
    ushort_t* bufA   = (ushort_t*)d_ws;                    // 38.4 MB bf16
    ushort_t* bufB   = bufA + tab;                         // 38.4 MB bf16
    float* accs      = (float*)(bufB + tab);               // 2 MB f32
    int2*  recs      = (int2*)(accs + (size_t)2 * NSEL * D);  // 25.6 MB
    int*   counts    = (int*)(recs + NEDGES);              // 600 KB
    int*   row_start = counts + NNODES;                    // 600 KB
    int*   cursor    = row_start + NNODES + 1;             // 600 KB
    int*   bsums     = cursor + NNODES;                    // 2.4 KB

    // ---- build CSR (counting sort by row, windowed scatter) ----
    k_zero_int<<<256, 256, 0, stream>>>(counts, NNODES);
    k_count<<<4096, 256, 0, stream>>>(edge_row, counts);
    k_blocksum<<<NB, 256, 0, stream>>>(counts, bsums);
    k_scanbsums<<<1, 1024, 0, stream>>>(bsums);
    k_scanfinal<<<NB, 256, 0, stream>>>(counts, bsums, row_start, cursor);
    for (int p = 0; p < NPASS; ++p)
        k_scatter_pass<<<2048, 256, 0, stream>>>(edge_row, edge_col, edge_val,
                                                 cursor, recs, p * ROWS_PER_PASS);

    // ---- embeddings ----
    k_init_bf16<<<2048, 256, 0, stream>>>((const float4*)user_emb, (const float4*)item_emb,
                                          (uint4*)bufA);
    k_sel0<<<(2 * NSEL * D) / 256, 256, 0, stream>>>(user_emb, item_emb, users, items, accs);

    // layer 1: full
    k_spmm_csr<<<(NNODES + 3) / 4, 256, 0, stream>>>((const uint_t*)bufA, (uint_t*)bufB,
                                                     row_start, recs);
    k_sel_bf16<<<(2 * NSEL * D) / 256, 256, 0, stream>>>(bufB, users, items, accs);
    // layer 2: full
    k_spmm_csr<<<(NNODES + 3) / 4, 256, 0, stream>>>((const uint_t*)bufB, (uint_t*)bufA,
                                                     row_start, recs);
    // layer 3 (selected rows only) fused with layer-2 k_sel
    k_spmm_sel<<<(2 * NSEL) / 4, 256, 0, stream>>>((const uint_t*)bufA, users, items,
                                                   row_start, recs, accs);

    k_dot<<<512, 256, 0, stream>>>(accs, out);
}

// Round 6
// 361.213 us; speedup vs baseline: 21.7382x; 1.6067x over previous
//
#include <hip/hip_runtime.h>

#define D 128
#define NUSERS 100000
#define NITEMS 50000
#define NNODES 150000
#define NEDGES 3200000
#define NSEL 2048
#define NBKT 586                 // ceil(150000 / 256) row-buckets of 256 rows
#define PBLK 256                 // partition blocks
#define EPB (NEDGES / PBLK)      // 12500 edges per partition block
#define MATN (NBKT * PBLK)       // 150016 (bucket-major count matrix)
#define MB ((MATN + 255) / 256)  // 586 scan blocks

typedef unsigned int uint_t;
typedef unsigned short ushort_t;

__device__ inline uint_t bf16_rne(float f) {
    uint_t x = __float_as_uint(f);
    return (x + 0x7FFFu + ((x >> 16) & 1u)) >> 16;
}

// cur(bf16) = concat(user_emb, item_emb); each thread converts 8 floats -> uint4
__global__ void k_init_bf16(const float4* __restrict__ u4, const float4* __restrict__ i4,
                            uint4* __restrict__ cur) {
    size_t total8 = (size_t)NNODES * D / 8;
    size_t ub8 = (size_t)NUSERS * D / 8;
    size_t stride = (size_t)gridDim.x * blockDim.x;
    for (size_t i = (size_t)blockIdx.x * blockDim.x + threadIdx.x; i < total8; i += stride) {
        const float4* src = (i < ub8) ? &u4[2 * i] : &i4[2 * (i - ub8)];
        float4 a = src[0], b = src[1];
        uint4 o;
        o.x = (bf16_rne(a.y) << 16) | bf16_rne(a.x);
        o.y = (bf16_rne(a.w) << 16) | bf16_rne(a.z);
        o.z = (bf16_rne(b.y) << 16) | bf16_rne(b.x);
        o.w = (bf16_rne(b.w) << 16) | bf16_rne(b.z);
        cur[i] = o;
    }
}

// ---- generic block exclusive scan helper ----
__device__ inline int block_excl_scan(int v, int* lds, int nw) {
    int lane = threadIdx.x & 63;
    int wid = (int)(threadIdx.x >> 6);
    int x = v;
    #pragma unroll
    for (int off = 1; off < 64; off <<= 1) {
        int y = __shfl_up(x, off);
        if (lane >= off) x += y;
    }
    if (lane == 63) lds[wid] = x;
    __syncthreads();
    if (wid == 0) {
        int s = (lane < nw) ? lds[lane] : 0;
        #pragma unroll
        for (int off = 1; off < 16; off <<= 1) {
            int y = __shfl_up(s, off);
            if (lane >= off) s += y;
        }
        if (lane < nw) lds[lane] = s;
    }
    __syncthreads();
    int waveoff = (wid == 0) ? 0 : lds[wid - 1];
    return waveoff + x - v;
}

// P1: per-block LDS bucket histogram -> mat[bucket][block]  (no global atomics)
__global__ void k_p1(const int* __restrict__ row, int* __restrict__ mat) {
    __shared__ int h[NBKT];
    for (int i = threadIdx.x; i < NBKT; i += 256) h[i] = 0;
    __syncthreads();
    int beg = blockIdx.x * EPB, end = beg + EPB;
    for (int e = beg + threadIdx.x; e < end; e += 256)
        atomicAdd(&h[row[e] >> 8], 1);
    __syncthreads();
    for (int i = threadIdx.x; i < NBKT; i += 256)
        mat[i * PBLK + blockIdx.x] = h[i];
}

__global__ void k_blocksum(const int* __restrict__ src, int* __restrict__ bsums, int n) {
    int i = blockIdx.x * 256 + threadIdx.x;
    int v = (i < n) ? src[i] : 0;
    #pragma unroll
    for (int off = 32; off; off >>= 1) v += __shfl_down(v, off);
    __shared__ int lds[4];
    int lane = threadIdx.x & 63, wid = (int)(threadIdx.x >> 6);
    if (lane == 0) lds[wid] = v;
    __syncthreads();
    if (threadIdx.x == 0) bsums[blockIdx.x] = lds[0] + lds[1] + lds[2] + lds[3];
}

__global__ void k_scanbsums(int* __restrict__ bsums, int nb) {
    __shared__ int lds[16];
    int t = threadIdx.x;
    int v = (t < nb) ? bsums[t] : 0;
    int ex = block_excl_scan(v, lds, 16);
    if (t < nb) bsums[t] = ex;
}

// in-place exclusive scan finalize: mat[i] = bsums[blk] + local exclusive
__global__ void k_scan_inplace(int* __restrict__ mat, const int* __restrict__ bsums, int n) {
    __shared__ int lds[4];
    int i = blockIdx.x * 256 + threadIdx.x;
    int v = (i < n) ? mat[i] : 0;
    int ex = block_excl_scan(v, lds, 4);
    if (i < n) mat[i] = bsums[blockIdx.x] + ex;
}

// P2: partition scatter using LDS cursors seeded from scanned mat (no global atomics)
__global__ void k_p2(const int* __restrict__ row, const int* __restrict__ col,
                     const float* __restrict__ val, const int* __restrict__ mat,
                     int2* __restrict__ tmp) {
    __shared__ int cur[NBKT];
    for (int i = threadIdx.x; i < NBKT; i += 256)
        cur[i] = mat[i * PBLK + blockIdx.x];
    __syncthreads();
    int beg = blockIdx.x * EPB, end = beg + EPB;
    for (int e = beg + threadIdx.x; e < end; e += 256) {
        int r = row[e];
        int b = r >> 8;
        int pos = atomicAdd(&cur[b], 1);
        int2 rc;
        rc.x = ((r & 255) << 24) | col[e];   // col < 2^24
        rc.y = __float_as_int(val[e]);
        tmp[pos] = rc;
    }
}

// P3: per-bucket exact CSR: 256-row LDS histogram + scan -> row_start + final records
__global__ void k_p3(const int2* __restrict__ tmp, const int* __restrict__ mat,
                     int2* __restrict__ recs, int* __restrict__ row_start) {
    int b = blockIdx.x;
    int beg = mat[b * PBLK];
    int end = (b + 1 < NBKT) ? mat[(b + 1) * PBLK] : NEDGES;
    __shared__ int h[256];
    __shared__ int lds[4];
    h[threadIdx.x] = 0;
    __syncthreads();
    for (int e = beg + threadIdx.x; e < end; e += 256)
        atomicAdd(&h[((uint_t)tmp[e].x) >> 24], 1);
    __syncthreads();
    int ex = block_excl_scan(h[threadIdx.x], lds, 4);
    int rowid = b * 256 + threadIdx.x;
    if (rowid < NNODES) row_start[rowid] = beg + ex;
    if (b == NBKT - 1 && threadIdx.x == 0) row_start[NNODES] = NEDGES;
    h[threadIdx.x] = ex;       // becomes the per-row LDS cursor
    __syncthreads();
    for (int e = beg + threadIdx.x; e < end; e += 256) {
        int2 rc = tmp[e];
        int lr = ((uint_t)rc.x) >> 24;
        int pos = beg + atomicAdd(&h[lr], 1);
        int2 o;
        o.x = rc.x & 0xFFFFFF;
        o.y = rc.y;
        recs[pos] = o;
    }
}

// CSR SpMM on bf16 table: one wave per row, lane handles 2 elems (one uint),
// f32 accumulate, RNE bf16 store
__global__ void k_spmm_csr(const uint_t* __restrict__ emb, uint_t* __restrict__ outp,
                           const int* __restrict__ row_start,
                           const int2* __restrict__ recs) {
    int lane = threadIdx.x & 63;
    int w = (int)((blockIdx.x * blockDim.x + threadIdx.x) >> 6);
    if (w >= NNODES) return;
    int beg = __builtin_amdgcn_readfirstlane(row_start[w]);
    int end = __builtin_amdgcn_readfirstlane(row_start[w + 1]);
    float ax = 0.f, ay = 0.f;
    int e = beg;
    for (; e + 3 < end; e += 4) {
        int2 r0 = recs[e], r1 = recs[e + 1], r2 = recs[e + 2], r3 = recs[e + 3];
        uint_t g0 = emb[(size_t)r0.x * 64 + lane];
        uint_t g1 = emb[(size_t)r1.x * 64 + lane];
        uint_t g2 = emb[(size_t)r2.x * 64 + lane];
        uint_t g3 = emb[(size_t)r3.x * 64 + lane];
        float v0 = __int_as_float(r0.y), v1 = __int_as_float(r1.y);
        float v2 = __int_as_float(r2.y), v3 = __int_as_float(r3.y);
        ax += v0 * __uint_as_float(g0 << 16) + v1 * __uint_as_float(g1 << 16)
            + v2 * __uint_as_float(g2 << 16) + v3 * __uint_as_float(g3 << 16);
        ay += v0 * __uint_as_float(g0 & 0xFFFF0000u) + v1 * __uint_as_float(g1 & 0xFFFF0000u)
            + v2 * __uint_as_float(g2 & 0xFFFF0000u) + v3 * __uint_as_float(g3 & 0xFFFF0000u);
    }
    for (; e < end; ++e) {
        int2 r0 = recs[e];
        float v = __int_as_float(r0.y);
        uint_t g = emb[(size_t)r0.x * 64 + lane];
        ax += v * __uint_as_float(g << 16);
        ay += v * __uint_as_float(g & 0xFFFF0000u);
    }
    outp[(size_t)w * 64 + lane] = (bf16_rne(ay) << 16) | bf16_rne(ax);
}

// layer-3 SpMM at selected rows only, fused with acc += emb[node]
__global__ void k_spmm_sel(const uint_t* __restrict__ emb,
                           const int* __restrict__ users, const int* __restrict__ items,
                           const int* __restrict__ row_start,
                           const int2* __restrict__ recs,
                           float* __restrict__ acc) {
    int lane = threadIdx.x & 63;
    int w = (int)((blockIdx.x * blockDim.x + threadIdx.x) >> 6);
    if (w >= 2 * NSEL) return;
    int node = (w < NSEL) ? users[w] : NUSERS + items[w - NSEL];
    int beg = __builtin_amdgcn_readfirstlane(row_start[node]);
    int end = __builtin_amdgcn_readfirstlane(row_start[node + 1]);
    uint_t e2 = emb[(size_t)node * 64 + lane];
    float ax = __uint_as_float(e2 << 16);
    float ay = __uint_as_float(e2 & 0xFFFF0000u);
    for (int e = beg; e < end; ++e) {
        int2 r0 = recs[e];
        float v = __int_as_float(r0.y);
        uint_t g = emb[(size_t)r0.x * 64 + lane];
        ax += v * __uint_as_float(g << 16);
        ay += v * __uint_as_float(g & 0xFFFF0000u);
    }
    float2* p = (float2*)&acc[(size_t)w * D + lane * 2];
    float2 r = *p;
    r.x += ax; r.y += ay;
    *p = r;
}

// layer-0 gather from the f32 inputs (set mode)
__global__ void k_sel0(const float* __restrict__ user_emb, const float* __restrict__ item_emb,
                       const int* __restrict__ users, const int* __restrict__ items,
                       float* __restrict__ acc) {
    int idx = blockIdx.x * blockDim.x + threadIdx.x;
    if (idx >= 2 * NSEL * D) return;
    int r = idx >> 7;
    int d = idx & (D - 1);
    const float* src = (r < NSEL) ? &user_emb[(size_t)users[r] * D]
                                  : &item_emb[(size_t)items[r - NSEL] * D];
    acc[idx] = src[d];
}

// gather selected rows from bf16 table, add into acc
__global__ void k_sel_bf16(const ushort_t* __restrict__ src,
                           const int* __restrict__ users, const int* __restrict__ items,
                           float* __restrict__ acc) {
    int idx = blockIdx.x * blockDim.x + threadIdx.x;
    if (idx >= 2 * NSEL * D) return;
    int r = idx >> 7;
    int d = idx & (D - 1);
    size_t node = (r < NSEL) ? (size_t)users[r] : (size_t)NUSERS + (size_t)items[r - NSEL];
    uint_t u = (uint_t)src[node * D + d] << 16;
    acc[idx] += __uint_as_float(u);
}

// one wave per output: gamma[i] = dot(accU[i], accI[i]) / 16
__global__ void k_dot(const float* __restrict__ acc, float* __restrict__ out) {
    int lane = threadIdx.x & 63;
    int w = (int)((blockIdx.x * blockDim.x + threadIdx.x) >> 6);
    if (w >= NSEL) return;
    const float* u = &acc[(size_t)w * D];
    const float* it = &acc[(size_t)(NSEL + w) * D];
    float s = u[lane] * it[lane] + u[lane + 64] * it[lane + 64];
    #pragma unroll
    for (int off = 32; off; off >>= 1) s += __shfl_down(s, off);
    if (lane == 0) out[w] = s * (1.0f / 16.0f);
}

extern "C" void kernel_launch(void* const* d_in, const int* in_sizes, int n_in,
                              void* d_out, int out_size, void* d_ws, size_t ws_size,
                              hipStream_t stream) {
    const float* user_emb = (const float*)d_in[0];
    const float* item_emb = (const float*)d_in[1];
    const float* edge_val = (const float*)d_in[2];
    const int*   edge_row = (const int*)d_in[3];
    const int*   edge_col = (const int*)d_in[4];
    const int*   users    = (const int*)d_in[5];
    const int*   items    = (const int*)d_in[6];
    float* out = (float*)d_out;

    const size_t tab = (size_t)NNODES * D;                     // elements
    ushort_t* bufA   = (ushort_t*)d_ws;                        // 38.4 MB bf16
    ushort_t* bufB   = bufA + tab;                             // 38.4 MB bf16
    float* accs      = (float*)(bufB + tab);                   // 2 MB f32
    int2*  recs      = (int2*)(accs + (size_t)2 * NSEL * D);   // 25.6 MB
    int2*  tmp       = recs + NEDGES;                          // 25.6 MB
    int*   mat       = (int*)(tmp + NEDGES);                   // 600 KB
    int*   row_start = mat + MATN;                             // 600 KB
    int*   bsums     = row_start + NNODES + 1;                 // 2.4 KB

    // ---- build CSR: atomic-free radix partition + per-bucket LDS sort ----
    k_p1<<<PBLK, 256, 0, stream>>>(edge_row, mat);
    k_blocksum<<<MB, 256, 0, stream>>>(mat, bsums, MATN);
    k_scanbsums<<<1, 1024, 0, stream>>>(bsums, MB);
    k_scan_inplace<<<MB, 256, 0, stream>>>(mat, bsums, MATN);
    k_p2<<<PBLK, 256, 0, stream>>>(edge_row, edge_col, edge_val, mat, tmp);
    k_p3<<<NBKT, 256, 0, stream>>>(tmp, mat, recs, row_start);

    // ---- embeddings ----
    k_init_bf16<<<2048, 256, 0, stream>>>((const float4*)user_emb, (const float4*)item_emb,
                                          (uint4*)bufA);
    k_sel0<<<(2 * NSEL * D) / 256, 256, 0, stream>>>(user_emb, item_emb, users, items, accs);

    // layer 1: full
    k_spmm_csr<<<(NNODES + 3) / 4, 256, 0, stream>>>((const uint_t*)bufA, (uint_t*)bufB,
                                                     row_start, recs);
    k_sel_bf16<<<(2 * NSEL * D) / 256, 256, 0, stream>>>(bufB, users, items, accs);
    // layer 2: full
    k_spmm_csr<<<(NNODES + 3) / 4, 256, 0, stream>>>((const uint_t*)bufB, (uint_t*)bufA,
                                                     row_start, recs);
    // layer 3 (selected rows only) fused with layer-2 k_sel
    k_spmm_sel<<<(2 * NSEL) / 4, 256, 0, stream>>>((const uint_t*)bufA, users, items,
                                                   row_start, recs, accs);

    k_dot<<<512, 256, 0, stream>>>(accs, out);
}